// Round 2
// baseline (687.253 us; speedup 1.0000x reference)
//
#include <hip/hip_runtime.h>
#include <hip/hip_bf16.h>

#define HIDDEN 768
#define HEADS 12
#define HEAD_DIM 64
#define BATCH 128
#define SEQ 196
#define M_TOT (BATCH * SEQ)   /* 25088 */
#define QKV_N (3 * HIDDEN)    /* 2304  */

typedef __attribute__((ext_vector_type(8))) short bf16x8;
typedef __attribute__((ext_vector_type(4))) float f32x4;

// round-to-nearest-even f32 -> bf16 (bit pattern)
__device__ __forceinline__ unsigned short f2bf(float f) {
    unsigned int u = __builtin_bit_cast(unsigned int, f);
    unsigned int r = (u + 0x7fffu + ((u >> 16) & 1u)) >> 16;
    return (unsigned short)r;
}

__device__ __forceinline__ ushort4 cvt4(float4 v) {
    ushort4 o;
    o.x = f2bf(v.x); o.y = f2bf(v.y); o.z = f2bf(v.z); o.w = f2bf(v.w);
    return o;
}

// ---------------------------------------------------------------------------
// prep: cast x -> bf16; build fused Wqkv [2304,768] bf16 (rows: Wq|Wk|Wv);
// cast Wp -> bf16; fuse biases [2304] f32.
// ---------------------------------------------------------------------------
__global__ __launch_bounds__(256) void prep_kernel(
    const float* __restrict__ x,
    const float* __restrict__ Wq, const float* __restrict__ Wk,
    const float* __restrict__ Wv, const float* __restrict__ Wp,
    const float* __restrict__ bq, const float* __restrict__ bk,
    const float* __restrict__ bv,
    unsigned short* __restrict__ xb, unsigned short* __restrict__ wqkv,
    unsigned short* __restrict__ wpb, float* __restrict__ biasq)
{
    const long long NX = (long long)M_TOT * HIDDEN / 4;        // 4816896
    const long long NQ = NX + (long long)QKV_N * HIDDEN / 4;   // +442368
    const long long NP = NQ + (long long)HIDDEN * HIDDEN / 4;  // +147456
    const long long NB = NP + QKV_N / 4;                       // +576
    long long tid = (long long)blockIdx.x * 256 + threadIdx.x;
    if (tid < NX) {
        float4 v = ((const float4*)x)[tid];
        ((ushort4*)xb)[tid] = cvt4(v);
    } else if (tid < NQ) {
        int i = (int)(tid - NX);
        int e = i * 4;
        int row = e / HIDDEN, col = e % HIDDEN;
        const float* s = (row < HIDDEN) ? (Wq + (size_t)row * HIDDEN + col)
                       : (row < 2 * HIDDEN) ? (Wk + (size_t)(row - HIDDEN) * HIDDEN + col)
                       : (Wv + (size_t)(row - 2 * HIDDEN) * HIDDEN + col);
        ((ushort4*)wqkv)[i] = cvt4(*(const float4*)s);
    } else if (tid < NP) {
        int i = (int)(tid - NQ);
        ((ushort4*)wpb)[i] = cvt4(((const float4*)Wp)[i]);
    } else if (tid < NB) {
        int i = (int)(tid - NP);
        int e = i * 4;
        const float* s = (e < HIDDEN) ? (bq + e)
                       : (e < 2 * HIDDEN) ? (bk + (e - HIDDEN))
                       : (bv + (e - 2 * HIDDEN));
        *(float4*)(biasq + e) = *(const float4*)s;
    }
}

// ---------------------------------------------------------------------------
// m97-style GEMM: C[M,Ncols] = A[M,768] * B[Ncols,768]^T + bias
// 128x128 tile, BK=32, 16x16x32 bf16 MFMA, 4 waves each doing 64x64 (4x4 acc),
// global_load_lds width-16 staging. M, Ncols, K all exact multiples.
// ---------------------------------------------------------------------------
template <bool OUT_BF16>
__global__ __launch_bounds__(256) void gemm_bt(
    const unsigned short* __restrict__ A,
    const unsigned short* __restrict__ B,
    const float* __restrict__ bias,
    void* __restrict__ C, const int Ncols)
{
    constexpr int K = HIDDEN;
    __shared__ __align__(16) unsigned short As[128 * 32];
    __shared__ __align__(16) unsigned short Bs[128 * 32];
    const int t = threadIdx.x, w = t >> 6, lane = t & 63;
    const int m0 = blockIdx.y * 128, n0 = blockIdx.x * 128;
    const int wm = w >> 1, wn = w & 1;
    const int srow = lane >> 2, scol = (lane & 3) * 8;
    f32x4 acc[4][4] = {};
    const unsigned short* ag0 = A + (size_t)(m0 + w * 16 + srow) * K + scol;
    const unsigned short* bg0 = B + (size_t)(n0 + w * 16 + srow) * K + scol;
    const int l15 = lane & 15, q8 = (lane >> 4) * 8;

    for (int k0 = 0; k0 < K; k0 += 32) {
#pragma unroll
        for (int it = 0; it < 2; ++it) {
            __builtin_amdgcn_global_load_lds(
                (__attribute__((address_space(1))) void*)(ag0 + (size_t)it * 64 * K + k0),
                (__attribute__((address_space(3))) void*)(As + it * 2048 + w * 512),
                16, 0, 0);
            __builtin_amdgcn_global_load_lds(
                (__attribute__((address_space(1))) void*)(bg0 + (size_t)it * 64 * K + k0),
                (__attribute__((address_space(3))) void*)(Bs + it * 2048 + w * 512),
                16, 0, 0);
        }
        __syncthreads();
        bf16x8 af[4], bfv[4];
#pragma unroll
        for (int i = 0; i < 4; ++i) {
            af[i]  = *(const bf16x8*)(As + (wm * 64 + i * 16 + l15) * 32 + q8);
            bfv[i] = *(const bf16x8*)(Bs + (wn * 64 + i * 16 + l15) * 32 + q8);
        }
#pragma unroll
        for (int i = 0; i < 4; ++i)
#pragma unroll
            for (int j = 0; j < 4; ++j)
                acc[i][j] = __builtin_amdgcn_mfma_f32_16x16x32_bf16(af[i], bfv[j], acc[i][j], 0, 0, 0);
        __syncthreads();
    }

    const int quad = lane >> 4;
#pragma unroll
    for (int j = 0; j < 4; ++j) {
        const int c = n0 + wn * 64 + j * 16 + l15;
        const float bv = bias[c];
#pragma unroll
        for (int i = 0; i < 4; ++i) {
            const int r0 = m0 + wm * 64 + i * 16 + quad * 4;
#pragma unroll
            for (int r = 0; r < 4; ++r) {
                float v = acc[i][j][r] + bv;
                size_t idx = (size_t)(r0 + r) * Ncols + c;
                if constexpr (OUT_BF16) ((unsigned short*)C)[idx] = f2bf(v);
                else                    ((float*)C)[idx] = v;
            }
        }
    }
}

// ---------------------------------------------------------------------------
// attention v2: one block per (b,h), 4 waves, wave w owns Q-tiles {w, w+4, ...}.
// Computes S^T via mfma(kf, qf): C-layout lane l15 = q-row, quad*4+r = key.
//  -> softmax row lives in ONE lane (over 13x4 regs) + 2 cross-quad shuffles
//  -> pos_bias/mask load as float4/int4 (contiguous keys)
//  -> PV A-frag (lane l15 = q-row) built by cross-quad shuffles, NO Ps LDS.
// Only LDS: Vt[64 rows d][256 keys], XOR-swizzled 8-key blocks so both the
// staging writes and the vf b128 reads are conflict-free/2-way.
// LDS = 32768 B -> 4-5 blocks/CU (vs 2 before). One barrier total.
// ---------------------------------------------------------------------------
__global__ __launch_bounds__(256, 4) void attn_kernel(
    const unsigned short* __restrict__ QKV,
    const float* __restrict__ pos_bias,
    const int* __restrict__ mask,
    unsigned short* __restrict__ ctx)
{
    __shared__ __align__(16) unsigned short Vt[64 * 256];  // 32768 B, swizzled
    const int b = blockIdx.x / HEADS, h = blockIdx.x % HEADS;
    const int t = threadIdx.x, w = t >> 6, lane = t & 63;
    const int quad = lane >> 4, l15 = lane & 15;
    const size_t base = (size_t)b * SEQ * QKV_N + h * HEAD_DIM;

    // zero pad keys 196..255 (swizzled addresses)
    for (int i = t; i < 64 * 60; i += 256) {
        int row = i / 60, key = 196 + i % 60;
        int s = (row & 7) ^ ((row >> 3) & 7);
        Vt[row * 256 + ((((key >> 3) ^ s) << 3) | (key & 7))] = 0;
    }
    // stage V transposed + swizzled: Vt[d][key'] = V[key][d]
    for (int c = t; c < SEQ * 8; c += 256) {
        int key = c >> 3, d0 = (c & 7) * 8;
        bf16x8 vv = *(const bf16x8*)(QKV + base + (size_t)key * QKV_N + 2 * HIDDEN + d0);
        int cb = key >> 3, kk = key & 7;
#pragma unroll
        for (int j = 0; j < 8; ++j) {
            int row = d0 + j;
            int s = (row & 7) ^ ((row >> 3) & 7);
            Vt[row * 256 + (((cb ^ s) << 3) | kk)] = (unsigned short)vv[j];
        }
    }
    __syncthreads();

    // per-lane swizzle constants for vf reads: rows rr = nt*16 + l15
    int vs[4];
#pragma unroll
    for (int nt = 0; nt < 4; ++nt) {
        int rr = nt * 16 + l15;
        vs[nt] = (rr & 7) ^ ((rr >> 3) & 7);
    }

    for (int t16 = w; t16 < 13; t16 += 4) {
        const int qrow = min(t16 * 16 + l15, SEQ - 1);
        const unsigned short* qp = QKV + base + (size_t)qrow * QKV_N + quad * 8;
        bf16x8 qf0 = *(const bf16x8*)(qp);
        bf16x8 qf1 = *(const bf16x8*)(qp + 32);

        f32x4 accT[13];
#pragma unroll
        for (int jt = 0; jt < 13; ++jt) {
            const int krow = min(jt * 16 + l15, SEQ - 1);
            const unsigned short* kp = QKV + base + (size_t)krow * QKV_N + HIDDEN + quad * 8;
            bf16x8 kf0 = *(const bf16x8*)(kp);
            bf16x8 kf1 = *(const bf16x8*)(kp + 32);
            f32x4 z = {};
            z = __builtin_amdgcn_mfma_f32_16x16x32_bf16(kf0, qf0, z, 0, 0, 0);
            z = __builtin_amdgcn_mfma_f32_16x16x32_bf16(kf1, qf1, z, 0, 0, 0);
            accT[jt] = z;  // S^T: lane l15 = q-row, key = jt*16 + quad*4 + r
        }

        // bias + mask + softmax (full attention row per lane)
        float mx = -3e38f;
#pragma unroll
        for (int jt = 0; jt < 13; ++jt) {
            const int key0 = jt * 16 + quad * 4;
            const int kb = min(key0, SEQ - 4);  // clamp float4/int4 base to 192
            float4 pb = *(const float4*)(pos_bias + (size_t)qrow * SEQ + kb);
            int4 mk = *(const int4*)(mask + b * SEQ + kb);
#pragma unroll
            for (int r = 0; r < 4; ++r) {
                const int key = key0 + r;
                const bool cv = (key < SEQ) && ((&mk.x)[r] != 0);
                float v = cv ? (accT[jt][r] * 0.125f + (&pb.x)[r]) : -1e30f;
                accT[jt][r] = v;
                mx = fmaxf(mx, v);
            }
        }
        mx = fmaxf(mx, __shfl_xor(mx, 16, 64));
        mx = fmaxf(mx, __shfl_xor(mx, 32, 64));
        float sm = 0.f;
#pragma unroll
        for (int jt = 0; jt < 13; ++jt)
#pragma unroll
            for (int r = 0; r < 4; ++r) {
                float e = __expf(accT[jt][r] - mx);
                accT[jt][r] = e;
                sm += e;
            }
        sm += __shfl_xor(sm, 16, 64);
        sm += __shfl_xor(sm, 32, 64);
        const float inv = 1.0f / sm;

        // pack P rows to bf16 pairs; tile 13 (keys 208..223) = 0
        unsigned int pk[14][2];
#pragma unroll
        for (int jt = 0; jt < 13; ++jt)
#pragma unroll
            for (int pp = 0; pp < 2; ++pp) {
                unsigned int lo = f2bf(accT[jt][2 * pp] * inv);
                unsigned int hi = f2bf(accT[jt][2 * pp + 1] * inv);
                pk[jt][pp] = (hi << 16) | lo;
            }
        pk[13][0] = 0; pk[13][1] = 0;

        // PV: A-frag lane l15 = q-row; k = quad*8 + j over 32-key chunks.
        // uint u of A-frag holds keys 32kt + 8*quad + 2u+{0,1}:
        //   source tile = 2kt + (quad>>1), source quad = 2*(quad&1) + (u>>1),
        //   source pair = u&1.
        f32x4 o[4] = {};
        const int hi_half = quad >> 1;
        const int sq0 = (quad & 1) * 2 * 16 + l15;   // src lane, u<2
        const int sq1 = sq0 + 16;                    // src lane, u>=2
#pragma unroll
        for (int kt = 0; kt < 7; ++kt) {
            union { unsigned int u[4]; bf16x8 v; } pf;
#pragma unroll
            for (int u = 0; u < 4; ++u) {
                const int src = (u < 2) ? sq0 : sq1;
                unsigned int a0 = (unsigned int)__shfl((int)pk[2 * kt][u & 1], src, 64);
                unsigned int a1 = (unsigned int)__shfl((int)pk[2 * kt + 1][u & 1], src, 64);
                pf.u[u] = hi_half ? a1 : a0;
            }
#pragma unroll
            for (int nt = 0; nt < 4; ++nt) {
                const int rr = nt * 16 + l15;
                const bf16x8 vf = *(const bf16x8*)(
                    &Vt[rr * 256 + (((kt * 4 + quad) ^ vs[nt]) << 3)]);
                o[nt] = __builtin_amdgcn_mfma_f32_16x16x32_bf16(pf.v, vf, o[nt], 0, 0, 0);
            }
        }

        // store ctx[b*196+row][h*64 + d]; row = t16*16 + quad*4 + r, d = nt*16+l15
#pragma unroll
        for (int nt = 0; nt < 4; ++nt)
#pragma unroll
            for (int r = 0; r < 4; ++r) {
                const int row = t16 * 16 + quad * 4 + r;
                if (row < SEQ)
                    ctx[((size_t)b * SEQ + row) * HIDDEN + h * HEAD_DIM + nt * 16 + l15] =
                        f2bf(o[nt][r]);
            }
    }
}

// ---------------------------------------------------------------------------
extern "C" void kernel_launch(void* const* d_in, const int* in_sizes, int n_in,
                              void* d_out, int out_size, void* d_ws, size_t ws_size,
                              hipStream_t stream) {
    const float* x    = (const float*)d_in[0];
    const float* Wq   = (const float*)d_in[1];
    const float* bq   = (const float*)d_in[2];
    const float* Wk   = (const float*)d_in[3];
    const float* bk   = (const float*)d_in[4];
    const float* Wv   = (const float*)d_in[5];
    const float* bv   = (const float*)d_in[6];
    const float* Wp   = (const float*)d_in[7];
    const float* bp   = (const float*)d_in[8];
    const float* pos  = (const float*)d_in[9];
    const int*   mask = (const int*)d_in[10];

    char* ws = (char*)d_ws;
    size_t off = 0;
    auto alloc = [&](size_t bytes) -> char* {
        char* p = ws + off;
        off += (bytes + 255) & ~(size_t)255;
        return p;
    };
    unsigned short* xb    = (unsigned short*)alloc((size_t)M_TOT * HIDDEN * 2);
    unsigned short* wqkv  = (unsigned short*)alloc((size_t)QKV_N * HIDDEN * 2);
    unsigned short* wpb   = (unsigned short*)alloc((size_t)HIDDEN * HIDDEN * 2);
    float*          biasq = (float*)alloc((size_t)QKV_N * 4);
    unsigned short* qkv   = (unsigned short*)alloc((size_t)M_TOT * QKV_N * 2);
    unsigned short* ctx   = (unsigned short*)alloc((size_t)M_TOT * HIDDEN * 2);

    prep_kernel<<<21123, 256, 0, stream>>>(x, Wq, Wk, Wv, Wp, bq, bk, bv,
                                           xb, wqkv, wpb, biasq);
    gemm_bt<true><<<dim3(QKV_N / 128, M_TOT / 128), 256, 0, stream>>>(
        xb, wqkv, biasq, (void*)qkv, QKV_N);
    attn_kernel<<<BATCH * HEADS, 256, 0, stream>>>(qkv, pos, mask, ctx);
    gemm_bt<false><<<dim3(HIDDEN / 128, M_TOT / 128), 256, 0, stream>>>(
        ctx, wpb, bp, d_out, HIDDEN);
}

// Round 3
// 486.417 us; speedup vs baseline: 1.4129x; 1.4129x over previous
//
#include <hip/hip_runtime.h>
#include <hip/hip_bf16.h>

#define HIDDEN 768
#define HEADS 12
#define HEAD_DIM 64
#define BATCH 128
#define SEQ 196
#define M_TOT (BATCH * SEQ)   /* 25088 */
#define QKV_N (3 * HIDDEN)    /* 2304  */

typedef __attribute__((ext_vector_type(8))) short bf16x8;
typedef __attribute__((ext_vector_type(4))) float f32x4;

// round-to-nearest-even f32 -> bf16 (bit pattern)
__device__ __forceinline__ unsigned short f2bf(float f) {
    unsigned int u = __builtin_bit_cast(unsigned int, f);
    unsigned int r = (u + 0x7fffu + ((u >> 16) & 1u)) >> 16;
    return (unsigned short)r;
}

__device__ __forceinline__ ushort4 cvt4(float4 v) {
    ushort4 o;
    o.x = f2bf(v.x); o.y = f2bf(v.y); o.z = f2bf(v.z); o.w = f2bf(v.w);
    return o;
}

// ---------------------------------------------------------------------------
// prep: cast x -> bf16; build fused Wqkv [2304,768] bf16 (rows: Wq|Wk|Wv);
// cast Wp -> bf16; fuse biases [2304] f32.
// ---------------------------------------------------------------------------
__global__ __launch_bounds__(256) void prep_kernel(
    const float* __restrict__ x,
    const float* __restrict__ Wq, const float* __restrict__ Wk,
    const float* __restrict__ Wv, const float* __restrict__ Wp,
    const float* __restrict__ bq, const float* __restrict__ bk,
    const float* __restrict__ bv,
    unsigned short* __restrict__ xb, unsigned short* __restrict__ wqkv,
    unsigned short* __restrict__ wpb, float* __restrict__ biasq)
{
    const long long NX = (long long)M_TOT * HIDDEN / 4;        // 4816896
    const long long NQ = NX + (long long)QKV_N * HIDDEN / 4;   // +442368
    const long long NP = NQ + (long long)HIDDEN * HIDDEN / 4;  // +147456
    const long long NB = NP + QKV_N / 4;                       // +576
    long long tid = (long long)blockIdx.x * 256 + threadIdx.x;
    if (tid < NX) {
        float4 v = ((const float4*)x)[tid];
        ((ushort4*)xb)[tid] = cvt4(v);
    } else if (tid < NQ) {
        int i = (int)(tid - NX);
        int e = i * 4;
        int row = e / HIDDEN, col = e % HIDDEN;
        const float* s = (row < HIDDEN) ? (Wq + (size_t)row * HIDDEN + col)
                       : (row < 2 * HIDDEN) ? (Wk + (size_t)(row - HIDDEN) * HIDDEN + col)
                       : (Wv + (size_t)(row - 2 * HIDDEN) * HIDDEN + col);
        ((ushort4*)wqkv)[i] = cvt4(*(const float4*)s);
    } else if (tid < NP) {
        int i = (int)(tid - NQ);
        ((ushort4*)wpb)[i] = cvt4(((const float4*)Wp)[i]);
    } else if (tid < NB) {
        int i = (int)(tid - NP);
        int e = i * 4;
        const float* s = (e < HIDDEN) ? (bq + e)
                       : (e < 2 * HIDDEN) ? (bk + (e - HIDDEN))
                       : (bv + (e - 2 * HIDDEN));
        *(float4*)(biasq + e) = *(const float4*)s;
    }
}

// ---------------------------------------------------------------------------
// m97-style GEMM: C[M,Ncols] = A[M,768] * B[Ncols,768]^T + bias
// ---------------------------------------------------------------------------
template <bool OUT_BF16>
__global__ __launch_bounds__(256) void gemm_bt(
    const unsigned short* __restrict__ A,
    const unsigned short* __restrict__ B,
    const float* __restrict__ bias,
    void* __restrict__ C, const int Ncols)
{
    constexpr int K = HIDDEN;
    __shared__ __align__(16) unsigned short As[128 * 32];
    __shared__ __align__(16) unsigned short Bs[128 * 32];
    const int t = threadIdx.x, w = t >> 6, lane = t & 63;
    const int m0 = blockIdx.y * 128, n0 = blockIdx.x * 128;
    const int wm = w >> 1, wn = w & 1;
    const int srow = lane >> 2, scol = (lane & 3) * 8;
    f32x4 acc[4][4] = {};
    const unsigned short* ag0 = A + (size_t)(m0 + w * 16 + srow) * K + scol;
    const unsigned short* bg0 = B + (size_t)(n0 + w * 16 + srow) * K + scol;
    const int l15 = lane & 15, q8 = (lane >> 4) * 8;

    for (int k0 = 0; k0 < K; k0 += 32) {
#pragma unroll
        for (int it = 0; it < 2; ++it) {
            __builtin_amdgcn_global_load_lds(
                (__attribute__((address_space(1))) void*)(ag0 + (size_t)it * 64 * K + k0),
                (__attribute__((address_space(3))) void*)(As + it * 2048 + w * 512),
                16, 0, 0);
            __builtin_amdgcn_global_load_lds(
                (__attribute__((address_space(1))) void*)(bg0 + (size_t)it * 64 * K + k0),
                (__attribute__((address_space(3))) void*)(Bs + it * 2048 + w * 512),
                16, 0, 0);
        }
        __syncthreads();
        bf16x8 af[4], bfv[4];
#pragma unroll
        for (int i = 0; i < 4; ++i) {
            af[i]  = *(const bf16x8*)(As + (wm * 64 + i * 16 + l15) * 32 + q8);
            bfv[i] = *(const bf16x8*)(Bs + (wn * 64 + i * 16 + l15) * 32 + q8);
        }
#pragma unroll
        for (int i = 0; i < 4; ++i)
#pragma unroll
            for (int j = 0; j < 4; ++j)
                acc[i][j] = __builtin_amdgcn_mfma_f32_16x16x32_bf16(af[i], bfv[j], acc[i][j], 0, 0, 0);
        __syncthreads();
    }

    const int quad = lane >> 4;
#pragma unroll
    for (int j = 0; j < 4; ++j) {
        const int c = n0 + wn * 64 + j * 16 + l15;
        const float bv = bias[c];
#pragma unroll
        for (int i = 0; i < 4; ++i) {
            const int r0 = m0 + wm * 64 + i * 16 + quad * 4;
#pragma unroll
            for (int r = 0; r < 4; ++r) {
                float v = acc[i][j][r] + bv;
                size_t idx = (size_t)(r0 + r) * Ncols + c;
                if constexpr (OUT_BF16) ((unsigned short*)C)[idx] = f2bf(v);
                else                    ((float*)C)[idx] = v;
            }
        }
    }
}

// ---------------------------------------------------------------------------
// attention v3: one block per (b,h), 4 waves, wave w owns Q-tiles {w, w+4, ...}.
// v2 compute structure (S^T via mfma(kf,qf), softmax row per lane, shuffle-built
// PV A-frags, no Ps buffer) + v3 data plan: K AND V staged in LDS once per
// block, so each Q/K/V byte is read from global exactly once (fixes the 587 MB
// HBM re-read that made v2 memory-bound).
//   Ks[208][72]: stride 72 elem = 36 dwords -> b128 reads conflict-free;
//                rows 196..207 zeroed (no clamp in inner loop).
//   Vt[64][256]: XOR-swizzled (R1-proven), conflict-free staging + reads.
// LDS = 62720 B -> 2 blocks/CU; one barrier total.
// ---------------------------------------------------------------------------
__global__ __launch_bounds__(256, 2) void attn_kernel(
    const unsigned short* __restrict__ QKV,
    const float* __restrict__ pos_bias,
    const int* __restrict__ mask,
    unsigned short* __restrict__ ctx)
{
    __shared__ __align__(16) unsigned short Ks[208 * 72];  // 29952 B
    __shared__ __align__(16) unsigned short Vt[64 * 256];  // 32768 B
    const int b = blockIdx.x / HEADS, h = blockIdx.x % HEADS;
    const int t = threadIdx.x, w = t >> 6, lane = t & 63;
    const int quad = lane >> 4, l15 = lane & 15;
    const size_t base = (size_t)b * SEQ * QKV_N + h * HEAD_DIM;

    // ---- stage K rows 0..195 (b128 in, b128 out), zero rows 196..207
    for (int c = t; c < SEQ * 8; c += 256) {
        int row = c >> 3, d0 = (c & 7) * 8;
        *(bf16x8*)(Ks + row * 72 + d0) =
            *(const bf16x8*)(QKV + base + (size_t)row * QKV_N + HIDDEN + d0);
    }
    {
        bf16x8 z = {};
        for (int i = t; i < 12 * 9; i += 256) {
            int row = 196 + i / 9, d0 = (i % 9) * 8;
            *(bf16x8*)(Ks + row * 72 + d0) = z;
        }
    }
    // ---- zero Vt pad keys 196..255 (swizzled addresses)
    for (int i = t; i < 64 * 60; i += 256) {
        int row = i / 60, key = 196 + i % 60;
        int s = (row & 7) ^ ((row >> 3) & 7);
        Vt[row * 256 + ((((key >> 3) ^ s) << 3) | (key & 7))] = 0;
    }
    // ---- stage V transposed + swizzled: Vt[d][key'] = V[key][d]
    for (int c = t; c < SEQ * 8; c += 256) {
        int key = c >> 3, d0 = (c & 7) * 8;
        bf16x8 vv = *(const bf16x8*)(QKV + base + (size_t)key * QKV_N + 2 * HIDDEN + d0);
        int cb = key >> 3, kk = key & 7;
#pragma unroll
        for (int j = 0; j < 8; ++j) {
            int row = d0 + j;
            int s = (row & 7) ^ ((row >> 3) & 7);
            Vt[row * 256 + (((cb ^ s) << 3) | kk)] = (unsigned short)vv[j];
        }
    }
    __syncthreads();

    // per-lane swizzle constants for vf reads: rows rr = nt*16 + l15
    int vs[4];
#pragma unroll
    for (int nt = 0; nt < 4; ++nt) {
        int rr = nt * 16 + l15;
        vs[nt] = (rr & 7) ^ ((rr >> 3) & 7);
    }

    for (int t16 = w; t16 < 13; t16 += 4) {
        const int qrow = min(t16 * 16 + l15, SEQ - 1);
        const unsigned short* qp = QKV + base + (size_t)qrow * QKV_N + quad * 8;
        bf16x8 qf0 = *(const bf16x8*)(qp);
        bf16x8 qf1 = *(const bf16x8*)(qp + 32);

        f32x4 accT[13];
#pragma unroll
        for (int jt = 0; jt < 13; ++jt) {
            const unsigned short* kp = Ks + (jt * 16 + l15) * 72 + quad * 8;
            bf16x8 kf0 = *(const bf16x8*)(kp);
            bf16x8 kf1 = *(const bf16x8*)(kp + 32);
            f32x4 z = {};
            z = __builtin_amdgcn_mfma_f32_16x16x32_bf16(kf0, qf0, z, 0, 0, 0);
            z = __builtin_amdgcn_mfma_f32_16x16x32_bf16(kf1, qf1, z, 0, 0, 0);
            accT[jt] = z;  // S^T: lane l15 = q-row, key = jt*16 + quad*4 + r
        }

        // bias + mask + softmax (full attention row per lane)
        float mx = -3e38f;
#pragma unroll
        for (int jt = 0; jt < 13; ++jt) {
            const int key0 = jt * 16 + quad * 4;
            const int kb = min(key0, SEQ - 4);  // clamp float4/int4 base to 192
            float4 pb = *(const float4*)(pos_bias + (size_t)qrow * SEQ + kb);
            int4 mk = *(const int4*)(mask + b * SEQ + kb);
#pragma unroll
            for (int r = 0; r < 4; ++r) {
                const int key = key0 + r;
                const bool cv = (key < SEQ) && ((&mk.x)[r] != 0);
                float v = cv ? (accT[jt][r] * 0.125f + (&pb.x)[r]) : -1e30f;
                accT[jt][r] = v;
                mx = fmaxf(mx, v);
            }
        }
        mx = fmaxf(mx, __shfl_xor(mx, 16, 64));
        mx = fmaxf(mx, __shfl_xor(mx, 32, 64));
        float sm = 0.f;
#pragma unroll
        for (int jt = 0; jt < 13; ++jt)
#pragma unroll
            for (int r = 0; r < 4; ++r) {
                float e = __expf(accT[jt][r] - mx);
                accT[jt][r] = e;
                sm += e;
            }
        sm += __shfl_xor(sm, 16, 64);
        sm += __shfl_xor(sm, 32, 64);
        const float inv = 1.0f / sm;

        // pack P rows to bf16 pairs; tile 13 (keys 208..223) = 0
        unsigned int pk[14][2];
#pragma unroll
        for (int jt = 0; jt < 13; ++jt)
#pragma unroll
            for (int pp = 0; pp < 2; ++pp) {
                unsigned int lo = f2bf(accT[jt][2 * pp] * inv);
                unsigned int hi = f2bf(accT[jt][2 * pp + 1] * inv);
                pk[jt][pp] = (hi << 16) | lo;
            }
        pk[13][0] = 0; pk[13][1] = 0;

        // PV: A-frag lane l15 = q-row; k = quad*8 + j over 32-key chunks.
        f32x4 o[4] = {};
        const int hi_half = quad >> 1;
        const int sq0 = (quad & 1) * 2 * 16 + l15;   // src lane, u<2
        const int sq1 = sq0 + 16;                    // src lane, u>=2
#pragma unroll
        for (int kt = 0; kt < 7; ++kt) {
            union { unsigned int u[4]; bf16x8 v; } pf;
#pragma unroll
            for (int u = 0; u < 4; ++u) {
                const int src = (u < 2) ? sq0 : sq1;
                unsigned int a0 = (unsigned int)__shfl((int)pk[2 * kt][u & 1], src, 64);
                unsigned int a1 = (unsigned int)__shfl((int)pk[2 * kt + 1][u & 1], src, 64);
                pf.u[u] = hi_half ? a1 : a0;
            }
#pragma unroll
            for (int nt = 0; nt < 4; ++nt) {
                const int rr = nt * 16 + l15;
                const bf16x8 vf = *(const bf16x8*)(
                    &Vt[rr * 256 + (((kt * 4 + quad) ^ vs[nt]) << 3)]);
                o[nt] = __builtin_amdgcn_mfma_f32_16x16x32_bf16(pf.v, vf, o[nt], 0, 0, 0);
            }
        }

        // store ctx[b*196+row][h*64 + d]; row = t16*16 + quad*4 + r, d = nt*16+l15
#pragma unroll
        for (int nt = 0; nt < 4; ++nt)
#pragma unroll
            for (int r = 0; r < 4; ++r) {
                const int row = t16 * 16 + quad * 4 + r;
                if (row < SEQ)
                    ctx[((size_t)b * SEQ + row) * HIDDEN + h * HEAD_DIM + nt * 16 + l15] =
                        f2bf(o[nt][r]);
            }
    }
}

// ---------------------------------------------------------------------------
extern "C" void kernel_launch(void* const* d_in, const int* in_sizes, int n_in,
                              void* d_out, int out_size, void* d_ws, size_t ws_size,
                              hipStream_t stream) {
    const float* x    = (const float*)d_in[0];
    const float* Wq   = (const float*)d_in[1];
    const float* bq   = (const float*)d_in[2];
    const float* Wk   = (const float*)d_in[3];
    const float* bk   = (const float*)d_in[4];
    const float* Wv   = (const float*)d_in[5];
    const float* bv   = (const float*)d_in[6];
    const float* Wp   = (const float*)d_in[7];
    const float* bp   = (const float*)d_in[8];
    const float* pos  = (const float*)d_in[9];
    const int*   mask = (const int*)d_in[10];

    char* ws = (char*)d_ws;
    size_t off = 0;
    auto alloc = [&](size_t bytes) -> char* {
        char* p = ws + off;
        off += (bytes + 255) & ~(size_t)255;
        return p;
    };
    unsigned short* xb    = (unsigned short*)alloc((size_t)M_TOT * HIDDEN * 2);
    unsigned short* wqkv  = (unsigned short*)alloc((size_t)QKV_N * HIDDEN * 2);
    unsigned short* wpb   = (unsigned short*)alloc((size_t)HIDDEN * HIDDEN * 2);
    float*          biasq = (float*)alloc((size_t)QKV_N * 4);
    unsigned short* qkv   = (unsigned short*)alloc((size_t)M_TOT * QKV_N * 2);
    unsigned short* ctx   = (unsigned short*)alloc((size_t)M_TOT * HIDDEN * 2);

    prep_kernel<<<21123, 256, 0, stream>>>(x, Wq, Wk, Wv, Wp, bq, bk, bv,
                                           xb, wqkv, wpb, biasq);
    gemm_bt<true><<<dim3(QKV_N / 128, M_TOT / 128), 256, 0, stream>>>(
        xb, wqkv, biasq, (void*)qkv, QKV_N);
    attn_kernel<<<BATCH * HEADS, 256, 0, stream>>>(qkv, pos, mask, ctx);
    gemm_bt<false><<<dim3(HIDDEN / 128, M_TOT / 128), 256, 0, stream>>>(
        ctx, wpb, bp, d_out, HIDDEN);
}

// Round 4
// 405.891 us; speedup vs baseline: 1.6932x; 1.1984x over previous
//
#include <hip/hip_runtime.h>
#include <hip/hip_bf16.h>

#define HIDDEN 768
#define HEADS 12
#define HEAD_DIM 64
#define BATCH 128
#define SEQ 196
#define M_TOT (BATCH * SEQ)   /* 25088 */
#define QKV_N (3 * HIDDEN)    /* 2304  */

typedef __attribute__((ext_vector_type(8))) short bf16x8;
typedef __attribute__((ext_vector_type(8))) unsigned short u16x8;
typedef __attribute__((ext_vector_type(4))) float f32x4;

// round-to-nearest-even f32 -> bf16 (bit pattern)
__device__ __forceinline__ unsigned short f2bf(float f) {
    unsigned int u = __builtin_bit_cast(unsigned int, f);
    unsigned int r = (u + 0x7fffu + ((u >> 16) & 1u)) >> 16;
    return (unsigned short)r;
}

__device__ __forceinline__ ushort4 cvt4(float4 v) {
    ushort4 o;
    o.x = f2bf(v.x); o.y = f2bf(v.y); o.z = f2bf(v.z); o.w = f2bf(v.w);
    return o;
}

// ---------------------------------------------------------------------------
// prep: cast x -> bf16; build fused Wqkv [2304,768] bf16 (rows: Wq|Wk|Wv);
// cast Wp -> bf16; fuse biases [2304] f32.
// ---------------------------------------------------------------------------
__global__ __launch_bounds__(256) void prep_kernel(
    const float* __restrict__ x,
    const float* __restrict__ Wq, const float* __restrict__ Wk,
    const float* __restrict__ Wv, const float* __restrict__ Wp,
    const float* __restrict__ bq, const float* __restrict__ bk,
    const float* __restrict__ bv,
    unsigned short* __restrict__ xb, unsigned short* __restrict__ wqkv,
    unsigned short* __restrict__ wpb, float* __restrict__ biasq)
{
    const long long NX = (long long)M_TOT * HIDDEN / 4;        // 4816896
    const long long NQ = NX + (long long)QKV_N * HIDDEN / 4;   // +442368
    const long long NP = NQ + (long long)HIDDEN * HIDDEN / 4;  // +147456
    const long long NB = NP + QKV_N / 4;                       // +576
    long long tid = (long long)blockIdx.x * 256 + threadIdx.x;
    if (tid < NX) {
        float4 v = ((const float4*)x)[tid];
        ((ushort4*)xb)[tid] = cvt4(v);
    } else if (tid < NQ) {
        int i = (int)(tid - NX);
        int e = i * 4;
        int row = e / HIDDEN, col = e % HIDDEN;
        const float* s = (row < HIDDEN) ? (Wq + (size_t)row * HIDDEN + col)
                       : (row < 2 * HIDDEN) ? (Wk + (size_t)(row - HIDDEN) * HIDDEN + col)
                       : (Wv + (size_t)(row - 2 * HIDDEN) * HIDDEN + col);
        ((ushort4*)wqkv)[i] = cvt4(*(const float4*)s);
    } else if (tid < NP) {
        int i = (int)(tid - NQ);
        ((ushort4*)wpb)[i] = cvt4(((const float4*)Wp)[i]);
    } else if (tid < NB) {
        int i = (int)(tid - NP);
        int e = i * 4;
        const float* s = (e < HIDDEN) ? (bq + e)
                       : (e < 2 * HIDDEN) ? (bk + (e - HIDDEN))
                       : (bv + (e - 2 * HIDDEN));
        *(float4*)(biasq + e) = *(const float4*)s;
    }
}

// ---------------------------------------------------------------------------
// m97-style GEMM: C[M,Ncols] = A[M,768] * B[Ncols,768]^T + bias
// R3: LDS-staged epilogue -> every global store is a full b128 lane-store,
// 8/16 lanes covering whole 128 B cache lines (kills 4x write amplification).
// ---------------------------------------------------------------------------
template <bool OUT_BF16>
__global__ __launch_bounds__(256) void gemm_bt(
    const unsigned short* __restrict__ A,
    const unsigned short* __restrict__ B,
    const float* __restrict__ bias,
    void* __restrict__ C, const int Ncols)
{
    constexpr int K = HIDDEN;
    __shared__ __align__(16) unsigned short As[128 * 32];
    __shared__ __align__(16) unsigned short Bs[128 * 32];
    __shared__ __align__(16) float Cs[4][16][68];   // 17408 B epilogue staging
    const int t = threadIdx.x, w = t >> 6, lane = t & 63;
    const int m0 = blockIdx.y * 128, n0 = blockIdx.x * 128;
    const int wm = w >> 1, wn = w & 1;
    const int srow = lane >> 2, scol = (lane & 3) * 8;
    f32x4 acc[4][4] = {};
    const unsigned short* ag0 = A + (size_t)(m0 + w * 16 + srow) * K + scol;
    const unsigned short* bg0 = B + (size_t)(n0 + w * 16 + srow) * K + scol;
    const int l15 = lane & 15, q8 = (lane >> 4) * 8;

    for (int k0 = 0; k0 < K; k0 += 32) {
#pragma unroll
        for (int it = 0; it < 2; ++it) {
            __builtin_amdgcn_global_load_lds(
                (__attribute__((address_space(1))) void*)(ag0 + (size_t)it * 64 * K + k0),
                (__attribute__((address_space(3))) void*)(As + it * 2048 + w * 512),
                16, 0, 0);
            __builtin_amdgcn_global_load_lds(
                (__attribute__((address_space(1))) void*)(bg0 + (size_t)it * 64 * K + k0),
                (__attribute__((address_space(3))) void*)(Bs + it * 2048 + w * 512),
                16, 0, 0);
        }
        __syncthreads();
        bf16x8 af[4], bfv[4];
#pragma unroll
        for (int i = 0; i < 4; ++i) {
            af[i]  = *(const bf16x8*)(As + (wm * 64 + i * 16 + l15) * 32 + q8);
            bfv[i] = *(const bf16x8*)(Bs + (wn * 64 + i * 16 + l15) * 32 + q8);
        }
#pragma unroll
        for (int i = 0; i < 4; ++i)
#pragma unroll
            for (int j = 0; j < 4; ++j)
                acc[i][j] = __builtin_amdgcn_mfma_f32_16x16x32_bf16(af[i], bfv[j], acc[i][j], 0, 0, 0);
        __syncthreads();
    }

    // ---- coalesced epilogue via LDS staging ----
    const int quad = lane >> 4;
    float bvj[4];
#pragma unroll
    for (int j = 0; j < 4; ++j) bvj[j] = bias[n0 + wn * 64 + j * 16 + l15];

#pragma unroll
    for (int i = 0; i < 4; ++i) {
        __syncthreads();  // WAR vs previous iteration's reads
#pragma unroll
        for (int j = 0; j < 4; ++j)
#pragma unroll
            for (int r = 0; r < 4; ++r)
                Cs[w][quad * 4 + r][j * 16 + l15] = acc[i][j][r] + bvj[j];
        __syncthreads();
        if constexpr (OUT_BF16) {
#pragma unroll
            for (int p = 0; p < 2; ++p) {
                const int row = p * 8 + (lane >> 3);
                const int c0 = (lane & 7) * 8;
                float4 a = *(const float4*)&Cs[w][row][c0];
                float4 bb = *(const float4*)&Cs[w][row][c0 + 4];
                u16x8 pk;
                pk[0] = f2bf(a.x); pk[1] = f2bf(a.y); pk[2] = f2bf(a.z); pk[3] = f2bf(a.w);
                pk[4] = f2bf(bb.x); pk[5] = f2bf(bb.y); pk[6] = f2bf(bb.z); pk[7] = f2bf(bb.w);
                *(u16x8*)((unsigned short*)C +
                          (size_t)(m0 + wm * 64 + i * 16 + row) * Ncols + n0 + wn * 64 + c0) = pk;
            }
        } else {
#pragma unroll
            for (int p = 0; p < 4; ++p) {
                const int row = p * 4 + (lane >> 4);
                const int c0 = (lane & 15) * 4;
                float4 a = *(const float4*)&Cs[w][row][c0];
                *(float4*)((float*)C +
                           (size_t)(m0 + wm * 64 + i * 16 + row) * Ncols + n0 + wn * 64 + c0) = a;
            }
        }
    }
}

// ---------------------------------------------------------------------------
// attention v4 = v3 + coalesced ctx stores.
// One block per (b,h), 4 waves, wave w owns Q-tiles {w, w+4, ...}.
// S^T via mfma(kf,qf); softmax row per lane; shuffle-built PV A-frags.
// K in Ks[208][72] (conflict-free b128), V in swizzled Vt[64][256].
// ctx stores staged through per-wave Os[16][72] bf16 -> b128 full-line stores
// (wave-local DS ordering: in-order DS unit + sched_barrier + lgkmcnt(0);
//  __syncthreads is NOT usable here - waves have unequal tile counts).
// LDS = 71936 B -> 2 blocks/CU.
// ---------------------------------------------------------------------------
__global__ __launch_bounds__(256, 2) void attn_kernel(
    const unsigned short* __restrict__ QKV,
    const float* __restrict__ pos_bias,
    const int* __restrict__ mask,
    unsigned short* __restrict__ ctx)
{
    __shared__ __align__(16) unsigned short Ks[208 * 72];     // 29952 B
    __shared__ __align__(16) unsigned short Vt[64 * 256];     // 32768 B
    __shared__ __align__(16) unsigned short Os[4][16 * 72];   //  9216 B
    const int b = blockIdx.x / HEADS, h = blockIdx.x % HEADS;
    const int t = threadIdx.x, w = t >> 6, lane = t & 63;
    const int quad = lane >> 4, l15 = lane & 15;
    const size_t base = (size_t)b * SEQ * QKV_N + h * HEAD_DIM;

    // ---- stage K rows 0..195 (b128 in, b128 out), zero rows 196..207
    for (int c = t; c < SEQ * 8; c += 256) {
        int row = c >> 3, d0 = (c & 7) * 8;
        *(bf16x8*)(Ks + row * 72 + d0) =
            *(const bf16x8*)(QKV + base + (size_t)row * QKV_N + HIDDEN + d0);
    }
    {
        bf16x8 z = {};
        for (int i = t; i < 12 * 9; i += 256) {
            int row = 196 + i / 9, d0 = (i % 9) * 8;
            *(bf16x8*)(Ks + row * 72 + d0) = z;
        }
    }
    // ---- zero Vt pad keys 196..255 (swizzled addresses)
    for (int i = t; i < 64 * 60; i += 256) {
        int row = i / 60, key = 196 + i % 60;
        int s = (row & 7) ^ ((row >> 3) & 7);
        Vt[row * 256 + ((((key >> 3) ^ s) << 3) | (key & 7))] = 0;
    }
    // ---- stage V transposed + swizzled: Vt[d][key'] = V[key][d]
    for (int c = t; c < SEQ * 8; c += 256) {
        int key = c >> 3, d0 = (c & 7) * 8;
        bf16x8 vv = *(const bf16x8*)(QKV + base + (size_t)key * QKV_N + 2 * HIDDEN + d0);
        int cb = key >> 3, kk = key & 7;
#pragma unroll
        for (int j = 0; j < 8; ++j) {
            int row = d0 + j;
            int s = (row & 7) ^ ((row >> 3) & 7);
            Vt[row * 256 + (((cb ^ s) << 3) | kk)] = (unsigned short)vv[j];
        }
    }
    __syncthreads();

    // per-lane swizzle constants for vf reads: rows rr = nt*16 + l15
    int vs[4];
#pragma unroll
    for (int nt = 0; nt < 4; ++nt) {
        int rr = nt * 16 + l15;
        vs[nt] = (rr & 7) ^ ((rr >> 3) & 7);
    }

    for (int t16 = w; t16 < 13; t16 += 4) {
        const int qrow = min(t16 * 16 + l15, SEQ - 1);
        const unsigned short* qp = QKV + base + (size_t)qrow * QKV_N + quad * 8;
        bf16x8 qf0 = *(const bf16x8*)(qp);
        bf16x8 qf1 = *(const bf16x8*)(qp + 32);

        f32x4 accT[13];
#pragma unroll
        for (int jt = 0; jt < 13; ++jt) {
            const unsigned short* kp = Ks + (jt * 16 + l15) * 72 + quad * 8;
            bf16x8 kf0 = *(const bf16x8*)(kp);
            bf16x8 kf1 = *(const bf16x8*)(kp + 32);
            f32x4 z = {};
            z = __builtin_amdgcn_mfma_f32_16x16x32_bf16(kf0, qf0, z, 0, 0, 0);
            z = __builtin_amdgcn_mfma_f32_16x16x32_bf16(kf1, qf1, z, 0, 0, 0);
            accT[jt] = z;  // S^T: lane l15 = q-row, key = jt*16 + quad*4 + r
        }

        // bias + mask + softmax (full attention row per lane)
        float mx = -3e38f;
#pragma unroll
        for (int jt = 0; jt < 13; ++jt) {
            const int key0 = jt * 16 + quad * 4;
            const int kb = min(key0, SEQ - 4);  // clamp float4/int4 base to 192
            float4 pb = *(const float4*)(pos_bias + (size_t)qrow * SEQ + kb);
            int4 mk = *(const int4*)(mask + b * SEQ + kb);
#pragma unroll
            for (int r = 0; r < 4; ++r) {
                const int key = key0 + r;
                const bool cv = (key < SEQ) && ((&mk.x)[r] != 0);
                float v = cv ? (accT[jt][r] * 0.125f + (&pb.x)[r]) : -1e30f;
                accT[jt][r] = v;
                mx = fmaxf(mx, v);
            }
        }
        mx = fmaxf(mx, __shfl_xor(mx, 16, 64));
        mx = fmaxf(mx, __shfl_xor(mx, 32, 64));
        float sm = 0.f;
#pragma unroll
        for (int jt = 0; jt < 13; ++jt)
#pragma unroll
            for (int r = 0; r < 4; ++r) {
                float e = __expf(accT[jt][r] - mx);
                accT[jt][r] = e;
                sm += e;
            }
        sm += __shfl_xor(sm, 16, 64);
        sm += __shfl_xor(sm, 32, 64);
        const float inv = 1.0f / sm;

        // pack P rows to bf16 pairs; tile 13 (keys 208..223) = 0
        unsigned int pk[14][2];
#pragma unroll
        for (int jt = 0; jt < 13; ++jt)
#pragma unroll
            for (int pp = 0; pp < 2; ++pp) {
                unsigned int lo = f2bf(accT[jt][2 * pp] * inv);
                unsigned int hi = f2bf(accT[jt][2 * pp + 1] * inv);
                pk[jt][pp] = (hi << 16) | lo;
            }
        pk[13][0] = 0; pk[13][1] = 0;

        // PV: A-frag lane l15 = q-row; k = quad*8 + j over 32-key chunks.
        f32x4 o[4] = {};
        const int hi_half = quad >> 1;
        const int sq0 = (quad & 1) * 2 * 16 + l15;   // src lane, u<2
        const int sq1 = sq0 + 16;                    // src lane, u>=2
#pragma unroll
        for (int kt = 0; kt < 7; ++kt) {
            union { unsigned int u[4]; bf16x8 v; } pf;
#pragma unroll
            for (int u = 0; u < 4; ++u) {
                const int src = (u < 2) ? sq0 : sq1;
                unsigned int a0 = (unsigned int)__shfl((int)pk[2 * kt][u & 1], src, 64);
                unsigned int a1 = (unsigned int)__shfl((int)pk[2 * kt + 1][u & 1], src, 64);
                pf.u[u] = hi_half ? a1 : a0;
            }
#pragma unroll
            for (int nt = 0; nt < 4; ++nt) {
                const int rr = nt * 16 + l15;
                const bf16x8 vf = *(const bf16x8*)(
                    &Vt[rr * 256 + (((kt * 4 + quad) ^ vs[nt]) << 3)]);
                o[nt] = __builtin_amdgcn_mfma_f32_16x16x32_bf16(pf.v, vf, o[nt], 0, 0, 0);
            }
        }

        // ---- coalesced ctx store: stage through per-wave Os, then b128 ----
        __builtin_amdgcn_sched_barrier(0);
#pragma unroll
        for (int nt = 0; nt < 4; ++nt)
#pragma unroll
            for (int r = 0; r < 4; ++r)
                Os[w][(quad * 4 + r) * 72 + nt * 16 + l15] = f2bf(o[nt][r]);
        __builtin_amdgcn_sched_barrier(0);
        asm volatile("s_waitcnt lgkmcnt(0)" ::: "memory");
#pragma unroll
        for (int p = 0; p < 2; ++p) {
            const int row = p * 8 + (lane >> 3);
            const int grow = t16 * 16 + row;
            const int c0 = (lane & 7) * 8;
            bf16x8 ov = *(const bf16x8*)&Os[w][row * 72 + c0];
            if (grow < SEQ)
                *(bf16x8*)(ctx + ((size_t)b * SEQ + grow) * HIDDEN + h * HEAD_DIM + c0) = ov;
        }
        __builtin_amdgcn_sched_barrier(0);
    }
}

// ---------------------------------------------------------------------------
extern "C" void kernel_launch(void* const* d_in, const int* in_sizes, int n_in,
                              void* d_out, int out_size, void* d_ws, size_t ws_size,
                              hipStream_t stream) {
    const float* x    = (const float*)d_in[0];
    const float* Wq   = (const float*)d_in[1];
    const float* bq   = (const float*)d_in[2];
    const float* Wk   = (const float*)d_in[3];
    const float* bk   = (const float*)d_in[4];
    const float* Wv   = (const float*)d_in[5];
    const float* bv   = (const float*)d_in[6];
    const float* Wp   = (const float*)d_in[7];
    const float* bp   = (const float*)d_in[8];
    const float* pos  = (const float*)d_in[9];
    const int*   mask = (const int*)d_in[10];

    char* ws = (char*)d_ws;
    size_t off = 0;
    auto alloc = [&](size_t bytes) -> char* {
        char* p = ws + off;
        off += (bytes + 255) & ~(size_t)255;
        return p;
    };
    unsigned short* xb    = (unsigned short*)alloc((size_t)M_TOT * HIDDEN * 2);
    unsigned short* wqkv  = (unsigned short*)alloc((size_t)QKV_N * HIDDEN * 2);
    unsigned short* wpb   = (unsigned short*)alloc((size_t)HIDDEN * HIDDEN * 2);
    float*          biasq = (float*)alloc((size_t)QKV_N * 4);
    unsigned short* qkv   = (unsigned short*)alloc((size_t)M_TOT * QKV_N * 2);
    unsigned short* ctx   = (unsigned short*)alloc((size_t)M_TOT * HIDDEN * 2);

    prep_kernel<<<21123, 256, 0, stream>>>(x, Wq, Wk, Wv, Wp, bq, bk, bv,
                                           xb, wqkv, wpb, biasq);
    gemm_bt<true><<<dim3(QKV_N / 128, M_TOT / 128), 256, 0, stream>>>(
        xb, wqkv, biasq, (void*)qkv, QKV_N);
    attn_kernel<<<BATCH * HEADS, 256, 0, stream>>>(qkv, pos, mask, ctx);
    gemm_bt<false><<<dim3(HIDDEN / 128, M_TOT / 128), 256, 0, stream>>>(
        ctx, wpb, bp, d_out, HIDDEN);
}